// Round 1
// 395.723 us; speedup vs baseline: 1.0380x; 1.0380x over previous
//
#include <hip/hip_runtime.h>
#include <hip/hip_bf16.h>
#include <cstdint>

#define NB 256
#define NF 1024
#define NDOF 64
#define NCLS 1000
#define CTILE 128
#define FGROUP 32
#define ROWSTR 68   /* bf16 per LDS row: 64 data + 4 pad = 136 B (b64 conflict-free) */

typedef __attribute__((ext_vector_type(8))) short short8;
typedef __attribute__((ext_vector_type(16))) float floatx16;

static __device__ inline unsigned short bfu(float f) {   // RNE f32->bf16 via HW cvt
    __hip_bfloat16 h = __float2bfloat16(f);
    union { __hip_bfloat16 h; unsigned short u; } cv;
    cv.h = h;
    return cv.u;
}

// ---------------- Phase 1: meta[f][b] = {P0 = bf(wA) | bf(wB)<<16, t}.
// wA = (mx-mn)*lam1 @ vertex t, wB = (mx-mn)*lam0 @ vertex t+1.
// bf16 conversion happens HERE (once per (f,b)) instead of per class-block.
// 32x32 LDS transpose tiles, 256 blocks: coalesced x reads AND meta writes.
__global__ __launch_bounds__(256) void lagr_meta(
    const float* __restrict__ x, const float* __restrict__ mnp,
    const float* __restrict__ mxp, uint2* __restrict__ meta)
{
    __shared__ uint2 tile[32][33];
    int f0 = blockIdx.x * 32;
    int b0 = blockIdx.y * 32;
    int tid = threadIdx.x;
    float mn = mnp[0], mx = mxp[0];
    float scale = mx - mn;
    float inv = 63.0f / scale;

    int fl = tid & 31, br = tid >> 5;
#pragma unroll
    for (int i = 0; i < 4; ++i) {
        int bl = br + i * 8;
        float xv = x[(size_t)(b0 + bl) * NF + f0 + fl];
        float s = (xv - mn) * inv;
        float wA = 0.0f, wB = 0.0f;
        uint32_t t = 0u;
        if (s >= 0.0f && s <= 63.0f) {
            float tf = floorf(s);
            if (tf > 62.0f) tf = 62.0f;
            t  = (uint32_t)tf;
            wA = scale * (tf + 1.0f - s);
            wB = scale * (s - tf);
        }
        uint32_t P0 = (uint32_t)bfu(wA) | ((uint32_t)bfu(wB) << 16);
        tile[fl][bl] = make_uint2(P0, t);
    }
    __syncthreads();
    int bl = tid & 31, fr = tid >> 5;
#pragma unroll
    for (int i = 0; i < 4; ++i) {
        int f = fr + i * 8;
        meta[(size_t)(f0 + f) * NB + b0 + bl] = tile[f][bl];
    }
}

// ---------------- Phase 2: per f, out += V_f (256x64, 2 nz/row) @ W_f^T via
// bf16 MFMA. Block = 512 thr (8 waves): wave w owns b-rows [32w, 32w+32),
// CTILE=128 classes (4 MFMA c-subtiles) -> A-build redundancy halved vs 64.
// Grid = 32 x 8 = 256 blocks = 1/CU; VGPR budget 256 (acc=64).
// A-frag build parity trick: pair base k0 is always even, so the (t,t+1) pair
// lands in ONE slot (t even: X0=P0) or TWO adjacent slots (t odd: X0=P0<<16 @
// t-1, X1=P0>>16 @ t+1) -> 2 cmp + 2 cndmask per slot.
__global__ __launch_bounds__(512, 2) void lagr_main(
    const uint2* __restrict__ meta, const float* __restrict__ W,
    const float* __restrict__ mnp, float* __restrict__ out)
{
    __shared__ unsigned short wt[2][CTILE * ROWSTR];   // 2 x 17408 B
    __shared__ float bias_s[CTILE];

    int tid  = threadIdx.x;
    int lane = tid & 63;
    int wave = tid >> 6;
    int half8 = (lane >> 5) << 3;        // k-offset of this half-wave
    int c0 = blockIdx.y * CTILE;
    int f0 = blockIdx.x * FGROUP;

    // staging roles: 4 threads per class row, 16 floats (64 B contiguous) each
    int cst = tid >> 2;
    int q4  = tid & 3;
    int crow = c0 + cst;
    if (crow > NCLS - 1) crow = NCLS - 1;
    const float* wrow = W + (size_t)crow * (NF * NDOF);

    floatx16 acc0, acc1, acc2, acc3;
#pragma unroll
    for (int r = 0; r < 16; ++r) { acc0[r] = 0.0f; acc1[r] = 0.0f; acc2[r] = 0.0f; acc3[r] = 0.0f; }
    float rowsum = 0.0f;

    float4 st[4];
    auto issue = [&](int f) {
        const float4* src = (const float4*)(wrow + ((size_t)f << 6)) + (q4 << 2);
        st[0] = src[0];
        st[1] = src[1];
        st[2] = src[2];
        st[3] = src[3];
    };
    auto commit = [&](unsigned short* buf) {
        float v[16] = { st[0].x, st[0].y, st[0].z, st[0].w,
                        st[1].x, st[1].y, st[1].z, st[1].w,
                        st[2].x, st[2].y, st[2].z, st[2].w,
                        st[3].x, st[3].y, st[3].z, st[3].w };
        uint32_t d[8];
#pragma unroll
        for (int i = 0; i < 8; ++i) {
            rowsum += v[2 * i] + v[2 * i + 1];
            d[i] = (uint32_t)bfu(v[2 * i]) | ((uint32_t)bfu(v[2 * i + 1]) << 16);
        }
        unsigned short* dst = buf + cst * ROWSTR + (q4 << 4);
        ((uint2*)dst)[0] = make_uint2(d[0], d[1]);   // ds_write_b64 x4
        ((uint2*)dst)[1] = make_uint2(d[2], d[3]);
        ((uint2*)dst)[2] = make_uint2(d[4], d[5]);
        ((uint2*)dst)[3] = make_uint2(d[6], d[7]);
    };

    unsigned short* cur = &wt[0][0];
    unsigned short* nxt = &wt[1][0];

    // this lane's b-row (A row m = lane&31); both half-waves share the same b
    const uint2* mbase = meta + wave * 32 + (lane & 31);
    uint2 mcur = mbase[(size_t)f0 * NB];

    issue(f0);
    commit(cur);
    __syncthreads();

#pragma unroll 1
    for (int ch = 0; ch < FGROUP; ++ch) {
        int f = f0 + ch;
        bool more = (ch + 1 < FGROUP);
        if (more) issue(f + 1);                        // prefetch next W chunk
        uint2 mnext = mcur;
        if (more) mnext = mbase[(size_t)(f + 1) * NB]; // prefetch next meta

        // ---- A-frags from meta (parity trick)
        uint32_t P0 = mcur.x;
        uint32_t t  = mcur.y;
        uint32_t odd = t & 1u;
        uint32_t X0 = odd ? (P0 << 16) : P0;
        uint32_t X1 = odd ? (P0 >> 16) : 0u;
        int d0 = (int)(t & ~1u) - half8;

        short8 afrag[4];
#pragma unroll
        for (int kc = 0; kc < 4; ++kc) {
            union { uint32_t u[4]; short8 v; } a;
#pragma unroll
            for (int q = 0; q < 4; ++q) {
                int C = kc * 16 + 2 * q;   // even pair-base (relative to half8)
                a.u[q] = (d0 == C) ? X0 : (d0 == C - 2) ? X1 : 0u;
            }
            afrag[kc] = a.v;
        }

        // ---- B-frags from LDS + MFMA (4 class sub-tiles)
        const unsigned short* rb = cur + (lane & 31) * ROWSTR + half8;
#define CTBODY(CT, ACC) { \
        const unsigned short* r = rb + (CT) * 32 * ROWSTR; \
        _Pragma("unroll") \
        for (int kc = 0; kc < 4; ++kc) { \
            union { uint2 u2[2]; short8 v; } bf; \
            bf.u2[0] = *(const uint2*)(r + kc * 16); \
            bf.u2[1] = *(const uint2*)(r + kc * 16 + 4); \
            ACC = __builtin_amdgcn_mfma_f32_32x32x16_bf16(afrag[kc], bf.v, ACC, 0, 0, 0); \
        } }
        CTBODY(0, acc0)
        CTBODY(1, acc1)
        CTBODY(2, acc2)
        CTBODY(3, acc3)
#undef CTBODY

        if (more) commit(nxt);
        unsigned short* tmp = cur; cur = nxt; nxt = tmp;
        mcur = mnext;
        __syncthreads();
    }

    // ---- bias = min_x * sum_k W[c,k] over this block's f-range
    rowsum += __shfl_xor(rowsum, 1);
    rowsum += __shfl_xor(rowsum, 2);
    if (q4 == 0) bias_s[cst] = mnp[0] * rowsum;
    __syncthreads();

    // ---- epilogue: C/D layout col=lane&31, row=(reg&3)+8*(reg>>2)+4*(lane>>5)
    int col = lane & 31;
    int rowhi = (lane >> 5) << 2;
#define EPI(CT, ACC) { \
        int c = c0 + (CT) * 32 + col; \
        if (c < NCLS) { \
            float bias = bias_s[(CT) * 32 + col]; \
            _Pragma("unroll") \
            for (int r = 0; r < 16; ++r) { \
                int brow = (r & 3) + 8 * (r >> 2) + rowhi; \
                atomicAdd(&out[(size_t)(wave * 32 + brow) * NCLS + c], ACC[r] + bias); \
            } } }
    EPI(0, acc0)
    EPI(1, acc1)
    EPI(2, acc2)
    EPI(3, acc3)
#undef EPI
}

extern "C" void kernel_launch(void* const* d_in, const int* in_sizes, int n_in,
                              void* d_out, int out_size, void* d_ws, size_t ws_size,
                              hipStream_t stream) {
    const float* x  = (const float*)d_in[0];
    const float* mn = (const float*)d_in[1];
    const float* mx = (const float*)d_in[2];
    const float* W  = (const float*)d_in[3];
    float* out = (float*)d_out;
    uint2* meta = (uint2*)d_ws;   // NF * NB * 8 B = 2 MB scratch

    hipMemsetAsync(d_out, 0, (size_t)NB * NCLS * sizeof(float), stream);

    lagr_meta<<<dim3(NF / 32, NB / 32), dim3(256), 0, stream>>>(x, mn, mx, meta);

    dim3 grid(NF / FGROUP, (NCLS + CTILE - 1) / CTILE);
    lagr_main<<<grid, dim3(512), 0, stream>>>(meta, W, mn, out);
}

// Round 2
// 385.216 us; speedup vs baseline: 1.0663x; 1.0273x over previous
//
#include <hip/hip_runtime.h>
#include <hip/hip_bf16.h>
#include <cstdint>

#define NB 256
#define NF 1024
#define NDOF 64
#define NCLS 1000
#define CTILE 128
#define FGROUP 32
#define NFB (NF / FGROUP)            /* 32 f-blocks = partial slices */
#define ROWSTR 68   /* bf16 per LDS row: 64 data + 4 pad = 136 B (b64 conflict-free) */

typedef __attribute__((ext_vector_type(8))) short short8;
typedef __attribute__((ext_vector_type(16))) float floatx16;

static __device__ inline unsigned short bfu(float f) {   // RNE f32->bf16 via HW cvt
    __hip_bfloat16 h = __float2bfloat16(f);
    union { __hip_bfloat16 h; unsigned short u; } cv;
    cv.h = h;
    return cv.u;
}

// ---------------- Phase 1: meta[f][b] = {P0 = bf(wA) | bf(wB)<<16, t}.
// wA = (mx-mn)*lam1 @ vertex t, wB = (mx-mn)*lam0 @ vertex t+1.
// 32x32 LDS transpose tiles: coalesced x reads AND coalesced meta writes.
__global__ __launch_bounds__(256) void lagr_meta(
    const float* __restrict__ x, const float* __restrict__ mnp,
    const float* __restrict__ mxp, uint2* __restrict__ meta)
{
    __shared__ uint2 tile[32][33];
    int f0 = blockIdx.x * 32;
    int b0 = blockIdx.y * 32;
    int tid = threadIdx.x;
    float mn = mnp[0], mx = mxp[0];
    float scale = mx - mn;
    float inv = 63.0f / scale;

    int fl = tid & 31, br = tid >> 5;
#pragma unroll
    for (int i = 0; i < 4; ++i) {
        int bl = br + i * 8;
        float xv = x[(size_t)(b0 + bl) * NF + f0 + fl];
        float s = (xv - mn) * inv;
        float wA = 0.0f, wB = 0.0f;
        uint32_t t = 0u;
        if (s >= 0.0f && s <= 63.0f) {
            float tf = floorf(s);
            if (tf > 62.0f) tf = 62.0f;
            t  = (uint32_t)tf;
            wA = scale * (tf + 1.0f - s);
            wB = scale * (s - tf);
        }
        uint32_t P0 = (uint32_t)bfu(wA) | ((uint32_t)bfu(wB) << 16);
        tile[fl][bl] = make_uint2(P0, t);
    }
    __syncthreads();
    int bl = tid & 31, fr = tid >> 5;
#pragma unroll
    for (int i = 0; i < 4; ++i) {
        int f = fr + i * 8;
        meta[(size_t)(f0 + f) * NB + b0 + bl] = tile[f][bl];
    }
}

// ---------------- Phase 2: per f, partial += V_f (256x64, 2 nz/row) @ W_f^T
// via bf16 MFMA. Block = 512 thr (8 waves): wave w owns b-rows [32w, 32w+32),
// CTILE=128 classes (4 MFMA c-subtiles). Grid = 32 x 8 = 256 blocks = 1/CU.
// NO ATOMICS: each f-block writes its own partial slice part[fb][b][c]
// (bias folded in); a reduce kernel sums the 32 slices.
__global__ __launch_bounds__(512, 2) void lagr_main(
    const uint2* __restrict__ meta, const float* __restrict__ W,
    const float* __restrict__ mnp, float* __restrict__ part)
{
    __shared__ unsigned short wt[2][CTILE * ROWSTR];   // 2 x 17408 B
    __shared__ float bias_s[CTILE];

    int tid  = threadIdx.x;
    int lane = tid & 63;
    int wave = tid >> 6;
    int half8 = (lane >> 5) << 3;        // k-offset of this half-wave
    int c0 = blockIdx.y * CTILE;
    int f0 = blockIdx.x * FGROUP;

    // staging roles: 4 threads per class row, 16 floats (64 B contiguous) each
    int cst = tid >> 2;
    int q4  = tid & 3;
    int crow = c0 + cst;
    if (crow > NCLS - 1) crow = NCLS - 1;
    const float* wrow = W + (size_t)crow * (NF * NDOF);

    floatx16 acc0, acc1, acc2, acc3;
#pragma unroll
    for (int r = 0; r < 16; ++r) { acc0[r] = 0.0f; acc1[r] = 0.0f; acc2[r] = 0.0f; acc3[r] = 0.0f; }
    float rowsum = 0.0f;

    float4 st[4];
    auto issue = [&](int f) {
        const float4* src = (const float4*)(wrow + ((size_t)f << 6)) + (q4 << 2);
        st[0] = src[0];
        st[1] = src[1];
        st[2] = src[2];
        st[3] = src[3];
    };
    auto commit = [&](unsigned short* buf) {
        float v[16] = { st[0].x, st[0].y, st[0].z, st[0].w,
                        st[1].x, st[1].y, st[1].z, st[1].w,
                        st[2].x, st[2].y, st[2].z, st[2].w,
                        st[3].x, st[3].y, st[3].z, st[3].w };
        uint32_t d[8];
#pragma unroll
        for (int i = 0; i < 8; ++i) {
            rowsum += v[2 * i] + v[2 * i + 1];
            d[i] = (uint32_t)bfu(v[2 * i]) | ((uint32_t)bfu(v[2 * i + 1]) << 16);
        }
        unsigned short* dst = buf + cst * ROWSTR + (q4 << 4);
        ((uint2*)dst)[0] = make_uint2(d[0], d[1]);   // ds_write_b64 x4
        ((uint2*)dst)[1] = make_uint2(d[2], d[3]);
        ((uint2*)dst)[2] = make_uint2(d[4], d[5]);
        ((uint2*)dst)[3] = make_uint2(d[6], d[7]);
    };

    unsigned short* cur = &wt[0][0];
    unsigned short* nxt = &wt[1][0];

    // this lane's b-row (A row m = lane&31); both half-waves share the same b
    const uint2* mbase = meta + wave * 32 + (lane & 31);
    uint2 mcur = mbase[(size_t)f0 * NB];

    issue(f0);
    commit(cur);
    __syncthreads();

#pragma unroll 1
    for (int ch = 0; ch < FGROUP; ++ch) {
        int f = f0 + ch;
        bool more = (ch + 1 < FGROUP);
        if (more) issue(f + 1);                        // prefetch next W chunk
        uint2 mnext = mcur;
        if (more) mnext = mbase[(size_t)(f + 1) * NB]; // prefetch next meta

        // ---- A-frags from meta (parity trick): pair base k0 always even, so
        // (t,t+1) lands in ONE slot (t even) or TWO adjacent slots (t odd).
        uint32_t P0 = mcur.x;
        uint32_t t  = mcur.y;
        uint32_t odd = t & 1u;
        uint32_t X0 = odd ? (P0 << 16) : P0;
        uint32_t X1 = odd ? (P0 >> 16) : 0u;
        int d0 = (int)(t & ~1u) - half8;

        short8 afrag[4];
#pragma unroll
        for (int kc = 0; kc < 4; ++kc) {
            union { uint32_t u[4]; short8 v; } a;
#pragma unroll
            for (int q = 0; q < 4; ++q) {
                int C = kc * 16 + 2 * q;   // even pair-base (relative to half8)
                a.u[q] = (d0 == C) ? X0 : (d0 == C - 2) ? X1 : 0u;
            }
            afrag[kc] = a.v;
        }

        // ---- B-frags from LDS + MFMA (4 class sub-tiles)
        const unsigned short* rb = cur + (lane & 31) * ROWSTR + half8;
#define CTBODY(CT, ACC) { \
        const unsigned short* r = rb + (CT) * 32 * ROWSTR; \
        _Pragma("unroll") \
        for (int kc = 0; kc < 4; ++kc) { \
            union { uint2 u2[2]; short8 v; } bf; \
            bf.u2[0] = *(const uint2*)(r + kc * 16); \
            bf.u2[1] = *(const uint2*)(r + kc * 16 + 4); \
            ACC = __builtin_amdgcn_mfma_f32_32x32x16_bf16(afrag[kc], bf.v, ACC, 0, 0, 0); \
        } }
        CTBODY(0, acc0)
        CTBODY(1, acc1)
        CTBODY(2, acc2)
        CTBODY(3, acc3)
#undef CTBODY

        if (more) commit(nxt);
        unsigned short* tmp = cur; cur = nxt; nxt = tmp;
        mcur = mnext;
        __syncthreads();
    }

    // ---- bias = min_x * sum_k W[c,k] over this block's f-range
    rowsum += __shfl_xor(rowsum, 1);
    rowsum += __shfl_xor(rowsum, 2);
    if (q4 == 0) bias_s[cst] = mnp[0] * rowsum;
    __syncthreads();

    // ---- epilogue: plain coalesced stores into this f-block's partial slice.
    // C/D layout col=lane&31, row=(reg&3)+8*(reg>>2)+4*(lane>>5)
    float* pslice = part + (size_t)blockIdx.x * NB * NCLS;
    int col = lane & 31;
    int rowhi = (lane >> 5) << 2;
#define EPI(CT, ACC) { \
        int c = c0 + (CT) * 32 + col; \
        if (c < NCLS) { \
            float bias = bias_s[(CT) * 32 + col]; \
            _Pragma("unroll") \
            for (int r = 0; r < 16; ++r) { \
                int brow = (r & 3) + 8 * (r >> 2) + rowhi; \
                pslice[(size_t)(wave * 32 + brow) * NCLS + c] = ACC[r] + bias; \
            } } }
    EPI(0, acc0)
    EPI(1, acc1)
    EPI(2, acc2)
    EPI(3, acc3)
#undef EPI
}

// ---------------- Phase 3: out[b][c] = sum_fb part[fb][b][c].
// Flat float4 over 256000 floats; 4 independent accumulator chains for ILP.
__global__ __launch_bounds__(256) void lagr_reduce(
    const float* __restrict__ part, float* __restrict__ out)
{
    int i = blockIdx.x * blockDim.x + threadIdx.x;     // float4 index, < 64000
    const float4* p = (const float4*)part;
    float4 a0 = make_float4(0.f, 0.f, 0.f, 0.f), a1 = a0, a2 = a0, a3 = a0;
    const int S = NB * NCLS / 4;                       // float4 stride per slice
#pragma unroll
    for (int fb = 0; fb < NFB; fb += 4) {
        float4 v0 = p[(size_t)(fb + 0) * S + i];
        float4 v1 = p[(size_t)(fb + 1) * S + i];
        float4 v2 = p[(size_t)(fb + 2) * S + i];
        float4 v3 = p[(size_t)(fb + 3) * S + i];
        a0.x += v0.x; a0.y += v0.y; a0.z += v0.z; a0.w += v0.w;
        a1.x += v1.x; a1.y += v1.y; a1.z += v1.z; a1.w += v1.w;
        a2.x += v2.x; a2.y += v2.y; a2.z += v2.z; a2.w += v2.w;
        a3.x += v3.x; a3.y += v3.y; a3.z += v3.z; a3.w += v3.w;
    }
    float4 r;
    r.x = (a0.x + a1.x) + (a2.x + a3.x);
    r.y = (a0.y + a1.y) + (a2.y + a3.y);
    r.z = (a0.z + a1.z) + (a2.z + a3.z);
    r.w = (a0.w + a1.w) + (a2.w + a3.w);
    ((float4*)out)[i] = r;
}

extern "C" void kernel_launch(void* const* d_in, const int* in_sizes, int n_in,
                              void* d_out, int out_size, void* d_ws, size_t ws_size,
                              hipStream_t stream) {
    const float* x  = (const float*)d_in[0];
    const float* mn = (const float*)d_in[1];
    const float* mx = (const float*)d_in[2];
    const float* W  = (const float*)d_in[3];
    float* out = (float*)d_out;
    uint2* meta = (uint2*)d_ws;                               // 2 MB
    float* part = (float*)((char*)d_ws + (size_t)NF * NB * 8); // 32 MB partials

    lagr_meta<<<dim3(NF / 32, NB / 32), dim3(256), 0, stream>>>(x, mn, mx, meta);

    dim3 grid(NF / FGROUP, (NCLS + CTILE - 1) / CTILE);
    lagr_main<<<grid, dim3(512), 0, stream>>>(meta, W, mn, part);

    lagr_reduce<<<dim3(NB * NCLS / 4 / 256), dim3(256), 0, stream>>>(part, out);
}